// Round 6
// baseline (310.985 us; speedup 1.0000x reference)
//
#include <hip/hip_runtime.h>

#define HEADS 8
#define DH 64
#define CO 3
#define E 192
#define NSEQ 2048
#define BATCH 2
#define CIN 256
#define DINNER 512
#define NTOK 4096
#define BHTOT 16

typedef __attribute__((ext_vector_type(8))) short bf16x8;
typedef __attribute__((ext_vector_type(4))) short bf16x4;
typedef __attribute__((ext_vector_type(4))) float f32x4;
typedef __attribute__((ext_vector_type(4))) float float4v;

static __device__ inline short f2bf(float f) {
  union { float f; unsigned u; } v; v.f = f;
  unsigned r = (v.u + 0x7FFFu + ((v.u >> 16) & 1u)) >> 16;  // RNE
  return (short)r;
}

static __device__ inline float bf2f(short s) {
  union { unsigned u; float f; } a;
  a.u = ((unsigned)(unsigned short)s) << 16;
  return a.f;
}

static __device__ inline void load_lds16(const short* g, short* l) {
  __builtin_amdgcn_global_load_lds(
      (const __attribute__((address_space(1))) void*)g,
      (__attribute__((address_space(3))) void*)l, 16, 0, 0);
}

// Frag-tile packing: a 16(row)x32(k) bf16 MFMA operand tile = 512 shorts,
// element [row r][k = qd*8+j] at (qd*16 + r)*8 + j (consuming wave's lane order).
// Internal e-order: e = c*64 + d.
// Key-axis permutation pi (PV position <-> key): within each 16, 4-key groups
// 1 and 2 swap (pi = involution). Applied to V rows in qkv_gemm so the attn
// P-exchange is exactly 2x permlane32_swap per q-fragment.

// ---------------------------------------------------------------- prep
__global__ __launch_bounds__(256) void prep(const float* __restrict__ x,
                                            const float* __restrict__ Wq,
                                            const float* __restrict__ Wk,
                                            const float* __restrict__ Wv,
                                            const float* __restrict__ Wo,
                                            short* __restrict__ xcp,
                                            short* __restrict__ wqkvp,
                                            short* __restrict__ wop) {
  int tid = threadIdx.x;
  if (blockIdx.x < 256) {
    __shared__ short st[12288];  // [c][ks][512]
    int mt = blockIdx.x;
    const float* xb = x + (size_t)mt * 12288;
#pragma unroll
    for (int r = 0; r < 12; r++) {
      int idx4 = r * 256 + tid;
      float4v v = *(const float4v*)(xb + idx4 * 4);
#pragma unroll
      for (int e = 0; e < 4; e++) {
        int fp = idx4 * 4 + e;
        int ti = fp / 3, c = fp - ti * 3;
        int tl = ti >> 8, i = ti & 255;
        int ks = i >> 5, qd = (i >> 3) & 3, j = i & 7;
        st[c * 4096 + ks * 512 + (qd * 16 + tl) * 8 + j] = f2bf(v[e]);
      }
    }
    __syncthreads();
    short* dst = xcp;
#pragma unroll
    for (int rep = 0; rep < 6; rep++) {
      int g = rep * 256 + tid;
      int c = g >> 9, rem = g & 511;
      *(bf16x8*)(dst + ((size_t)(c * 256 + mt) * 8) * 512 + rem * 8) =
          *(const bf16x8*)&st[c * 4096 + rem * 8];
    }
    return;
  }
  int idx = (blockIdx.x - 256) * 256 + tid;
  const float qscale = 0.07216878364870323f * 1.4426950408889634f;  // 192^-0.5 * log2(e)
  if (idx < 1536 * 256) {
    int o = idx >> 8, i = idx & 255;
    float v;
    if (o < 512) v = Wq[idx] * qscale;
    else if (o < 1024) v = Wk[idx - 512 * 256];
    else v = Wv[idx - 1024 * 256];
    int nt = o >> 4, ln = o & 15, ks = i >> 5, qd = (i >> 3) & 3, j = i & 7;
    wqkvp[((size_t)(nt * 8 + ks)) * 512 + (qd * 16 + ln) * 8 + j] = f2bf(v);
  } else {
    int j0 = idx - 1536 * 256;
    if (j0 < 256 * 512) {
      int o2 = j0 >> 9, i = j0 & 511;
      int nt = o2 >> 4, ln = o2 & 15, ks = i >> 5, qd = (i >> 3) & 3, j = i & 7;
      wop[((size_t)(nt * 16 + ks)) * 512 + (qd * 16 + ln) * 8 + j] = f2bf(Wo[j0]);
    }
  }
}

// ---------------------------------------------------------------- qkv_gemm v3
// (R14-proven) 128m x 64n tiles, grid (24,32,3). mat/h uniform per block.
// B-frags direct from L2-resident wqkvp; A staged 8 KB/iter double-buffered.
// V epilogue applies pi (quad 1<->2 swap) on the key axis.
__global__ __launch_bounds__(256, 4) void qkv_gemm(const short* __restrict__ xcp,
                                                   const short* __restrict__ wqkvp,
                                                   short* __restrict__ qp,
                                                   short* __restrict__ kp,
                                                   short* __restrict__ vp) {
  __shared__ __align__(16) short pool[9216];  // A dbuf 2x4096 | epilogue tp [128][72]
  int c = blockIdx.z, ntb = blockIdx.x, mtb = blockIdx.y;
  int tid = threadIdx.x, wave = tid >> 6, lane = tid & 63;
  int ln = lane & 15, quad = lane >> 4;
  int wm = wave >> 1, wn = wave & 1;

  const short* gA = xcp + ((size_t)(c * 256 + mtb * 8) * 8) * 512;

  f32x4 acc[4][2] = {};
#pragma unroll
  for (int i = 0; i < 2; i++) {
    int q = tid + 256 * i, mf = q >> 6, l = q & 63;
    load_lds16(gA + (size_t)(mf * 8) * 512 + l * 8, pool + q * 8);
  }
  for (int ks = 0; ks < 8; ks++) {
    int b = ks & 1;
    __syncthreads();
    if (ks < 7) {
#pragma unroll
      for (int i = 0; i < 2; i++) {
        int q = tid + 256 * i, mf = q >> 6, l = q & 63;
        load_lds16(gA + (size_t)(mf * 8 + ks + 1) * 512 + l * 8,
                   pool + (b ^ 1) * 4096 + q * 8);
      }
    }
    const short* As = pool + b * 4096;
    bf16x8 af[4], bfr[2];
#pragma unroll
    for (int j = 0; j < 2; j++)
      bfr[j] = *(const bf16x8*)(wqkvp +
          (size_t)((ntb * 4 + wn * 2 + j) * 8 + ks) * 512 + lane * 8);
#pragma unroll
    for (int i = 0; i < 4; i++) af[i] = *(const bf16x8*)&As[(wm * 4 + i) * 512 + lane * 8];
#pragma unroll
    for (int i = 0; i < 4; i++)
#pragma unroll
      for (int j = 0; j < 2; j++)
        acc[i][j] = __builtin_amdgcn_mfma_f32_16x16x32_bf16(af[i], bfr[j], acc[i][j], 0, 0, 0);
  }

  int mat = ntb >> 3;        // 0=Q 1=K 2=V (block-uniform)
  int h = ntb & 7;
  int b0 = mtb >> 4;
  int bhx = b0 * 8 + h;
  if (mat < 2) {
    __syncthreads();
    short* tp = pool;  // [128][72]: 9216 shorts; stride 72 = 36 dw (4 mod 32)
#pragma unroll
    for (int i = 0; i < 4; i++)
#pragma unroll
      for (int j = 0; j < 2; j++)
#pragma unroll
        for (int jj = 0; jj < 4; jj++)
          tp[(wm * 64 + i * 16 + quad * 4 + jj) * 72 + wn * 32 + j * 16 + ln] =
              f2bf(acc[i][j][jj]);
    __syncthreads();
    short* dst = (mat == 0) ? qp : kp;
#pragma unroll
    for (int rep = 0; rep < 4; rep++) {
      int gi = rep * 256 + tid;  // l2(4b) qd(2b) nf2(2b) esp(1b) kt2(1b)
      int l2 = gi & 15, qd = (gi >> 4) & 3, nf2 = (gi >> 6) & 3,
          esp = (gi >> 8) & 1, kt2 = (gi >> 9) & 1;
      int tl = kt2 * 64 + nf2 * 16 + l2;
      bf16x8 val = *(const bf16x8*)&tp[tl * 72 + esp * 32 + qd * 8];
      int kt = (mtb * 2 + kt2) & 31;
      int es = c * 2 + esp;
      size_t off = (((size_t)((bhx * 32 + kt) * 24) + es * 4 + nf2) * 64 +
                    (size_t)(qd * 16 + l2)) * 8;
      *(bf16x8*)(dst + off) = val;
    }
  } else {
    // pi on the key axis: key group (=quad) 1<->2 swap so attn's permlane
    // exchange lands P positions on matching V rows.
    int q2 = quad ^ (((quad ^ (quad >> 1)) & 1) * 3);  // 0,2,1,3
#pragma unroll
    for (int i = 0; i < 4; i++) {
      int kt = (mtb * 2 + wm) & 31;
      int ks2 = (i >> 1) & 1;
      int qd2 = (i * 2 + (q2 >> 1)) & 3;
#pragma unroll
      for (int j = 0; j < 2; j++) {
        int ef = c * 4 + wn * 2 + j;   // d = wn*32+j*16+ln -> d>>4 = wn*2+j
        size_t off = ((size_t)((bhx * 32 + kt) * 24 + ks2 * 12 + ef)) * 512 +
                     (qd2 * 16 + ln) * 8 + (q2 & 1) * 4;
        bf16x4 val = { f2bf(acc[i][j][0]), f2bf(acc[i][j][1]),
                       f2bf(acc[i][j][2]), f2bf(acc[i][j][3]) };
        *(bf16x4*)(vp + off) = val;
      }
    }
  }
}

// ---------------------------------------------------------------- attn v6
// R1's proven schedule (deferred PV, K/V in LDS, S^T swap, in-reg P exchange)
// restructured for 4 blocks/CU: templated split-K NKH (2 or 4), LDS cut to
// 36864 B via V SINGLE-buffer (second barrier/iter fences the WAR) and a
// 2-pass epilogue tp [64][200]. NKH=4: grid 1024 -> exactly 4 resident
// blocks/CU (16 waves) — doubles TLP at constant per-CU MFMA/LDS-read work.
// NKH=2 is the ws-too-small fallback (R1-equivalent schedule, grid 512).
template<int NKH>
__global__ __launch_bounds__(256, 4) void attn(const short* __restrict__ qp,
                                               const short* __restrict__ kp,
                                               const short* __restrict__ vp,
                                               short* __restrict__ opart,
                                               float* __restrict__ lpart) {
  constexpr int KITERS = 64 / NKH;   // 32-key tiles per block
  __shared__ __align__(16) short pool[18432];  // K dbuf 2x6144 | V 6144; tp overlay
  int pair = blockIdx.x, qt = blockIdx.y;
  int bh = pair & 15, kh = pair >> 4;
  int tid = threadIdx.x, wave = tid >> 6, lane = tid & 63;
  int ln = lane & 15, quad = lane >> 4;

  bf16x8 qf[2][6];
#pragma unroll
  for (int rg = 0; rg < 2; rg++) {
    int fi = wave * 2 + rg;
    const short* qb = qp +
        ((size_t)(bh * 32 + qt * 2 + (fi >> 2)) * 24 + (fi & 3)) * 512 + lane * 8;
#pragma unroll
    for (int es = 0; es < 6; es++) qf[rg][es] = *(const bf16x8*)(qb + es * 2048);
  }

  float l_r[2] = {0.f, 0.f};
  f32x4 acc[2][12] = {};
  bf16x8 pa[2] = {};  // P fragments of the previous key tile (registers)
  const short* gKb = kp + (size_t)(bh * 32 + kh * (32 / NKH)) * 12288;
  const short* gVb = vp + (size_t)(bh * 32 + kh * (32 / NKH)) * 12288;

  auto stage_k = [&](int k32) {
    const short* g64 = gKb + (size_t)(k32 >> 1) * 12288;
    int half = k32 & 1;
    short* Kd = pool + (k32 & 1) * 6144;
#pragma unroll
    for (int i = 0; i < 3; i++) {
      int q = i * 256 + tid;
      int f = q >> 6, l = q & 63;
      int es = f >> 1, nfl = f & 1;
      load_lds16(g64 + (size_t)(es * 4 + half * 2 + nfl) * 512 + l * 8, Kd + q * 8);
    }
  };
  auto stage_v = [&](int k32) {
    const short* g64 = gVb + (size_t)(k32 >> 1) * 12288;
    int half = k32 & 1;
    short* Vd = pool + 12288;  // single buffer
#pragma unroll
    for (int i = 0; i < 3; i++) {
      int q = i * 256 + tid;
      int f = q >> 6, l = q & 63;
      load_lds16(g64 + (size_t)(half * 12 + f) * 512 + l * 8, Vd + q * 8);
    }
  };

  stage_k(0);
  for (int kt = 0; kt < KITERS; kt++) {
    __syncthreads();   // barrier1: K(kt) and V(kt-1) deposits visible
    if (kt < KITERS - 1) stage_k(kt + 1);  // other K slot (its reads retired)
    const short* Kl = pool + (kt & 1) * 6144;
    const short* Vl = pool + 12288;        // V(kt-1); unused at kt=0

    __builtin_amdgcn_s_setprio(1);
    // S^T = K Q^T: row=key(quad*4+jj), col=qrow(ln)
    f32x4 s[2][2] = {};
#pragma unroll
    for (int es = 0; es < 6; es++) {
#pragma unroll
      for (int nfl = 0; nfl < 2; nfl++) {
        bf16x8 kf = *(const bf16x8*)&Kl[(es * 2 + nfl) * 512 + lane * 8];
        s[0][nfl] = __builtin_amdgcn_mfma_f32_16x16x32_bf16(kf, qf[0][es], s[0][nfl], 0, 0, 0);
        s[1][nfl] = __builtin_amdgcn_mfma_f32_16x16x32_bf16(kf, qf[1][es], s[1][nfl], 0, 0, 0);
      }
    }
    if (kt > 0) {
#pragma unroll
      for (int ef = 0; ef < 12; ef++) {
        bf16x8 v0 = *(const bf16x8*)&Vl[ef * 512 + lane * 8];
        acc[0][ef] = __builtin_amdgcn_mfma_f32_16x16x32_bf16(pa[0], v0, acc[0][ef], 0, 0, 0);
        acc[1][ef] = __builtin_amdgcn_mfma_f32_16x16x32_bf16(pa[1], v0, acc[1][ef], 0, 0, 0);
      }
    }
    __builtin_amdgcn_s_setprio(0);

    __syncthreads();   // barrier2: all PV reads of V(kt-1) retired
    stage_v(kt);       // overwrite V buf; consumed after next barrier1

    // softmax for tile kt (overlaps stage_v latency): exp2 -> bf16 pack ->
    // cross-half swap. Source lane (quad,ln) holds keys {nfl*16+quad*4+jj}
    // of q-row ln; after 2x permlane32_swap dest lane holds PV positions
    // quad*8..+7 = keys under pi — matching qkv_gemm's V layout.
#pragma unroll
    for (int rg = 0; rg < 2; rg++) {
      float p0[4], p1[4];
#pragma unroll
      for (int jj = 0; jj < 4; jj++) {
        float e0 = __builtin_amdgcn_exp2f(s[rg][0][jj]);
        float e1 = __builtin_amdgcn_exp2f(s[rg][1][jj]);
        p0[jj] = e0; p1[jj] = e1;
        l_r[rg] += e0;
        l_r[rg] += e1;
      }
      unsigned a0, a1, b0, b1;
      asm("v_cvt_pk_bf16_f32 %0, %1, %2" : "=v"(a0) : "v"(p0[0]), "v"(p0[1]));
      asm("v_cvt_pk_bf16_f32 %0, %1, %2" : "=v"(a1) : "v"(p0[2]), "v"(p0[3]));
      asm("v_cvt_pk_bf16_f32 %0, %1, %2" : "=v"(b0) : "v"(p1[0]), "v"(p1[1]));
      asm("v_cvt_pk_bf16_f32 %0, %1, %2" : "=v"(b1) : "v"(p1[2]), "v"(p1[3]));
      auto r0 = __builtin_amdgcn_permlane32_swap(a0, b0, false, false);
      auto r1 = __builtin_amdgcn_permlane32_swap(a1, b1, false, false);
      union { unsigned u[4]; bf16x8 v; } pk;
      pk.u[0] = r0[0]; pk.u[1] = r1[0]; pk.u[2] = r0[1]; pk.u[3] = r1[1];
      pa[rg] = pk.v;
    }
  }

  // Epilogue PV for the last tile: V(KITERS-1) deposits drained here.
  __syncthreads();
  {
    const short* Vl = pool + 12288;
#pragma unroll
    for (int ef = 0; ef < 12; ef++) {
      bf16x8 v0 = *(const bf16x8*)&Vl[ef * 512 + lane * 8];
      acc[0][ef] = __builtin_amdgcn_mfma_f32_16x16x32_bf16(pa[0], v0, acc[0][ef], 0, 0, 0);
      acc[1][ef] = __builtin_amdgcn_mfma_f32_16x16x32_bf16(pa[1], v0, acc[1][ef], 0, 0, 0);
    }
  }

  // l reduce: keys were distributed across quads (and nfl, already summed)
#pragma unroll
  for (int rg = 0; rg < 2; rg++) {
    l_r[rg] += __shfl_xor(l_r[rg], 16, 64);
    l_r[rg] += __shfl_xor(l_r[rg], 32, 64);
  }

  // 2-pass epilogue: tp [64][200] = 12800 shorts fits the 18432-short pool.
  // row mapping identical to R1: row = wave*32 + rg*16 + quad*4 + jj.
  const size_t obase = ((size_t)(kh * 16 + bh) * 2048 + qt * 128) * 192;
#pragma unroll
  for (int rg = 0; rg < 2; rg++) {
    __syncthreads();  // pass 0: epilogue-PV reads done; pass 1: tp reads done
    short* tp = pool;
#pragma unroll
    for (int jj = 0; jj < 4; jj++) {
      int r4 = wave * 16 + quad * 4 + jj;
#pragma unroll
      for (int ef = 0; ef < 12; ef++)
        tp[r4 * 200 + ef * 16 + ln] = f2bf(acc[rg][ef][jj]);
    }
    __syncthreads();
#pragma unroll
    for (int rep = 0; rep < 6; rep++) {
      int gi = rep * 256 + tid;
      int rowc = gi / 24, c8 = gi - rowc * 24;
      int row = (rowc >> 4) * 32 + rg * 16 + (rowc & 15);
      *(bf16x8*)(opart + obase + (size_t)row * 192 + c8 * 8) =
          *(const bf16x8*)&tp[rowc * 200 + c8 * 8];
    }
  }
  int lb = (kh * 16 + bh) * 2048 + qt * 128;
  if (quad == 0) {
#pragma unroll
    for (int rg = 0; rg < 2; rg++)
      lpart[lb + (wave * 2 + rg) * 16 + ln] = l_r[rg];
  }
}

// ---------------------------------------------------------------- out_gemm v5
// (R14-proven structure) c-FUSED merge + projection; grid 256; coalesced fp32
// output. Templated on NPART (number of split-K partials to merge).
template<int NPART>
__global__ __launch_bounds__(256) void out_gemm(const short* __restrict__ opart,
                                                const float* __restrict__ lpart,
                                                const short* __restrict__ wop,
                                                float* __restrict__ out) {
  __shared__ __align__(16) float pool_f[12352];  // 49408 B
  short* Al = (short*)pool_f;                    // [3][16 ks][512]
  int mtb = blockIdx.x;
  int tid = threadIdx.x, wave = tid >> 6, lane = tid & 63;
  int ln = lane & 15, quad = lane >> 4;
  const size_t HSTR = (size_t)16 * 2048 * 192;

#pragma unroll
  for (int rep = 0; rep < 12; rep++) {
    int g = rep * 256 + tid;
    int c = g >> 10, inner = g & 1023;
    int d8 = inner & 7, h = (inner >> 3) & 7, row16 = inner >> 6;
    int t = mtb * 16 + row16, b = t >> 11, n = t & 2047;
    int bh = b * 8 + h;
    size_t src = ((size_t)bh * 2048 + n) * 192 + c * 64 + d8 * 8;
    float l = 0.f;
#pragma unroll
    for (int p = 0; p < NPART; p++) l += lpart[((size_t)(p * 16 + bh)) * 2048 + n];
    float inv = 1.f / l;
    float a8[8] = {};
#pragma unroll
    for (int p = 0; p < NPART; p++) {
      bf16x8 o = *(const bf16x8*)(opart + (size_t)p * HSTR + src);
#pragma unroll
      for (int j = 0; j < 8; j++) a8[j] += bf2f(o[j]);
    }
    bf16x8 r;
#pragma unroll
    for (int j = 0; j < 8; j++) r[j] = f2bf(a8[j] * inv);
    int ks = h * 2 + (d8 >> 2), qd = d8 & 3;
    *(bf16x8*)&Al[c * 8192 + ks * 512 + (qd * 16 + row16) * 8] = r;
  }
  __syncthreads();

  f32x4 acc[3][4] = {};
  for (int ks = 0; ks < 16; ks++) {
    bf16x8 af[3];
#pragma unroll
    for (int c = 0; c < 3; c++) af[c] = *(const bf16x8*)&Al[c * 8192 + ks * 512 + lane * 8];
#pragma unroll
    for (int jf = 0; jf < 4; jf++) {
      int nt = wave * 4 + jf;
      bf16x8 bfr = *(const bf16x8*)(wop + (size_t)(nt * 16 + ks) * 512 + lane * 8);
#pragma unroll
      for (int c = 0; c < 3; c++)
        acc[c][jf] = __builtin_amdgcn_mfma_f32_16x16x32_bf16(af[c], bfr, acc[c][jf], 0, 0, 0);
    }
  }
  __syncthreads();  // Al dead; reuse pool_f for the fp32 out-tile [16][772]
#pragma unroll
  for (int c = 0; c < 3; c++)
#pragma unroll
    for (int jf = 0; jf < 4; jf++) {
      int o2 = (wave * 4 + jf) * 16 + ln;
#pragma unroll
      for (int jj = 0; jj < 4; jj++)
        pool_f[(quad * 4 + jj) * 772 + o2 * 3 + c] = acc[c][jf][jj];
    }
  __syncthreads();
  float* ob = out + (size_t)mtb * 12288;
#pragma unroll
  for (int rep = 0; rep < 12; rep++) {
    int idx = rep * 256 + tid;
    int row = idx / 192, col4 = idx - row * 192;
    *(float4v*)(ob + row * 768 + col4 * 4) =
        *(const float4v*)(pool_f + row * 772 + col4 * 4);
  }
}

// ---------------------------------------------------------------- launch
extern "C" void kernel_launch(void* const* d_in, const int* in_sizes, int n_in,
                              void* d_out, int out_size, void* d_ws, size_t ws_size,
                              hipStream_t stream) {
  const float* x  = (const float*)d_in[0];
  const float* Wq = (const float*)d_in[1];
  const float* Wk = (const float*)d_in[2];
  const float* Wv = (const float*)d_in[3];
  const float* Wo = (const float*)d_in[4];
  float* out = (float*)d_out;

  short* ws    = (short*)d_ws;
  short* xcp   = ws;                                   // 3*4096*256
  short* wqkvp = xcp + 3 * NTOK * CIN;                 // 1536*256
  short* wop   = wqkvp + 1536 * 256;                   // 256*512
  short* qp    = wop + 256 * 512;                      // 16*2048*192
  short* kp    = qp + (size_t)BHTOT * NSEQ * E;
  short* vp    = kp + (size_t)BHTOT * NSEQ * E;
  short* opart = vp + (size_t)BHTOT * NSEQ * E;        // NPART*16*2048*192
  float* lpart = (float*)xcp;   // ALIAS: xcp dead after qkv_gemm (stream order)

  // Runtime ws-size guard: split-K 4 needs 4 O-partials (~95.4 MB total ws).
  const size_t base_shorts = (size_t)(3 * NTOK * CIN) + 1536 * 256 + 256 * 512 +
                             3 * (size_t)BHTOT * NSEQ * E;
  const size_t need4 = (base_shorts + 4 * (size_t)BHTOT * NSEQ * E) * sizeof(short);
  bool p4 = ws_size >= need4;

  prep<<<2304, 256, 0, stream>>>(x, Wq, Wk, Wv, Wo, xcp, wqkvp, wop);
  qkv_gemm<<<dim3(24, 32, 3), 256, 0, stream>>>(xcp, wqkvp, qp, kp, vp);
  if (p4) {
    attn<4><<<dim3(64, 16), 256, 0, stream>>>(qp, kp, vp, opart, lpart);
    out_gemm<4><<<256, 256, 0, stream>>>(opart, lpart, wop, out);
  } else {
    attn<2><<<dim3(32, 16), 256, 0, stream>>>(qp, kp, vp, opart, lpart);
    out_gemm<2><<<256, 256, 0, stream>>>(opart, lpart, wop, out);
  }
}

// Round 7
// 154.085 us; speedup vs baseline: 2.0183x; 2.0183x over previous
//
#include <hip/hip_runtime.h>

#define HEADS 8
#define DH 64
#define CO 3
#define E 192
#define NSEQ 2048
#define BATCH 2
#define CIN 256
#define DINNER 512
#define NTOK 4096
#define BHTOT 16

typedef __attribute__((ext_vector_type(8))) short bf16x8;
typedef __attribute__((ext_vector_type(4))) short bf16x4;
typedef __attribute__((ext_vector_type(4))) float f32x4;
typedef __attribute__((ext_vector_type(4))) float float4v;

static __device__ inline short f2bf(float f) {
  union { float f; unsigned u; } v; v.f = f;
  unsigned r = (v.u + 0x7FFFu + ((v.u >> 16) & 1u)) >> 16;  // RNE
  return (short)r;
}

static __device__ inline float bf2f(short s) {
  union { unsigned u; float f; } a;
  a.u = ((unsigned)(unsigned short)s) << 16;
  return a.f;
}

static __device__ inline void load_lds16(const short* g, short* l) {
  __builtin_amdgcn_global_load_lds(
      (const __attribute__((address_space(1))) void*)g,
      (__attribute__((address_space(3))) void*)l, 16, 0, 0);
}

// Frag-tile packing: a 16(row)x32(k) bf16 MFMA operand tile = 512 shorts,
// element [row r][k = qd*8+j] at (qd*16 + r)*8 + j (consuming wave's lane order).
// Internal e-order: e = c*64 + d.
// Key-axis permutation pi (PV position <-> key): within each 16, 4-key groups
// 1 and 2 swap (pi = involution). Applied to V rows in qkv_gemm so the attn
// P-exchange is exactly 2x permlane32_swap per q-fragment.

// ---------------------------------------------------------------- prep
__global__ __launch_bounds__(256) void prep(const float* __restrict__ x,
                                            const float* __restrict__ Wq,
                                            const float* __restrict__ Wk,
                                            const float* __restrict__ Wv,
                                            const float* __restrict__ Wo,
                                            short* __restrict__ xcp,
                                            short* __restrict__ wqkvp,
                                            short* __restrict__ wop) {
  int tid = threadIdx.x;
  if (blockIdx.x < 256) {
    __shared__ short st[12288];  // [c][ks][512]
    int mt = blockIdx.x;
    const float* xb = x + (size_t)mt * 12288;
#pragma unroll
    for (int r = 0; r < 12; r++) {
      int idx4 = r * 256 + tid;
      float4v v = *(const float4v*)(xb + idx4 * 4);
#pragma unroll
      for (int e = 0; e < 4; e++) {
        int fp = idx4 * 4 + e;
        int ti = fp / 3, c = fp - ti * 3;
        int tl = ti >> 8, i = ti & 255;
        int ks = i >> 5, qd = (i >> 3) & 3, j = i & 7;
        st[c * 4096 + ks * 512 + (qd * 16 + tl) * 8 + j] = f2bf(v[e]);
      }
    }
    __syncthreads();
    short* dst = xcp;
#pragma unroll
    for (int rep = 0; rep < 6; rep++) {
      int g = rep * 256 + tid;
      int c = g >> 9, rem = g & 511;
      *(bf16x8*)(dst + ((size_t)(c * 256 + mt) * 8) * 512 + rem * 8) =
          *(const bf16x8*)&st[c * 4096 + rem * 8];
    }
    return;
  }
  int idx = (blockIdx.x - 256) * 256 + tid;
  const float qscale = 0.07216878364870323f * 1.4426950408889634f;  // 192^-0.5 * log2(e)
  if (idx < 1536 * 256) {
    int o = idx >> 8, i = idx & 255;
    float v;
    if (o < 512) v = Wq[idx] * qscale;
    else if (o < 1024) v = Wk[idx - 512 * 256];
    else v = Wv[idx - 1024 * 256];
    int nt = o >> 4, ln = o & 15, ks = i >> 5, qd = (i >> 3) & 3, j = i & 7;
    wqkvp[((size_t)(nt * 8 + ks)) * 512 + (qd * 16 + ln) * 8 + j] = f2bf(v);
  } else {
    int j0 = idx - 1536 * 256;
    if (j0 < 256 * 512) {
      int o2 = j0 >> 9, i = j0 & 511;
      int nt = o2 >> 4, ln = o2 & 15, ks = i >> 5, qd = (i >> 3) & 3, j = i & 7;
      wop[((size_t)(nt * 16 + ks)) * 512 + (qd * 16 + ln) * 8 + j] = f2bf(Wo[j0]);
    }
  }
}

// ---------------------------------------------------------------- qkv_gemm v3
// (R14-proven) 128m x 64n tiles, grid (24,32,3). mat/h uniform per block.
// B-frags direct from L2-resident wqkvp; A staged 8 KB/iter double-buffered.
// V epilogue applies pi (quad 1<->2 swap) on the key axis.
__global__ __launch_bounds__(256, 4) void qkv_gemm(const short* __restrict__ xcp,
                                                   const short* __restrict__ wqkvp,
                                                   short* __restrict__ qp,
                                                   short* __restrict__ kp,
                                                   short* __restrict__ vp) {
  __shared__ __align__(16) short pool[9216];  // A dbuf 2x4096 | epilogue tp [128][72]
  int c = blockIdx.z, ntb = blockIdx.x, mtb = blockIdx.y;
  int tid = threadIdx.x, wave = tid >> 6, lane = tid & 63;
  int ln = lane & 15, quad = lane >> 4;
  int wm = wave >> 1, wn = wave & 1;

  const short* gA = xcp + ((size_t)(c * 256 + mtb * 8) * 8) * 512;

  f32x4 acc[4][2] = {};
#pragma unroll
  for (int i = 0; i < 2; i++) {
    int q = tid + 256 * i, mf = q >> 6, l = q & 63;
    load_lds16(gA + (size_t)(mf * 8) * 512 + l * 8, pool + q * 8);
  }
  for (int ks = 0; ks < 8; ks++) {
    int b = ks & 1;
    __syncthreads();
    if (ks < 7) {
#pragma unroll
      for (int i = 0; i < 2; i++) {
        int q = tid + 256 * i, mf = q >> 6, l = q & 63;
        load_lds16(gA + (size_t)(mf * 8 + ks + 1) * 512 + l * 8,
                   pool + (b ^ 1) * 4096 + q * 8);
      }
    }
    const short* As = pool + b * 4096;
    bf16x8 af[4], bfr[2];
#pragma unroll
    for (int j = 0; j < 2; j++)
      bfr[j] = *(const bf16x8*)(wqkvp +
          (size_t)((ntb * 4 + wn * 2 + j) * 8 + ks) * 512 + lane * 8);
#pragma unroll
    for (int i = 0; i < 4; i++) af[i] = *(const bf16x8*)&As[(wm * 4 + i) * 512 + lane * 8];
#pragma unroll
    for (int i = 0; i < 4; i++)
#pragma unroll
      for (int j = 0; j < 2; j++)
        acc[i][j] = __builtin_amdgcn_mfma_f32_16x16x32_bf16(af[i], bfr[j], acc[i][j], 0, 0, 0);
  }

  int mat = ntb >> 3;        // 0=Q 1=K 2=V (block-uniform)
  int h = ntb & 7;
  int b0 = mtb >> 4;
  int bhx = b0 * 8 + h;
  if (mat < 2) {
    __syncthreads();
    short* tp = pool;  // [128][72]: 9216 shorts; stride 72 = 36 dw (4 mod 32)
#pragma unroll
    for (int i = 0; i < 4; i++)
#pragma unroll
      for (int j = 0; j < 2; j++)
#pragma unroll
        for (int jj = 0; jj < 4; jj++)
          tp[(wm * 64 + i * 16 + quad * 4 + jj) * 72 + wn * 32 + j * 16 + ln] =
              f2bf(acc[i][j][jj]);
    __syncthreads();
    short* dst = (mat == 0) ? qp : kp;
#pragma unroll
    for (int rep = 0; rep < 4; rep++) {
      int gi = rep * 256 + tid;  // l2(4b) qd(2b) nf2(2b) esp(1b) kt2(1b)
      int l2 = gi & 15, qd = (gi >> 4) & 3, nf2 = (gi >> 6) & 3,
          esp = (gi >> 8) & 1, kt2 = (gi >> 9) & 1;
      int tl = kt2 * 64 + nf2 * 16 + l2;
      bf16x8 val = *(const bf16x8*)&tp[tl * 72 + esp * 32 + qd * 8];
      int kt = (mtb * 2 + kt2) & 31;
      int es = c * 2 + esp;
      size_t off = (((size_t)((bhx * 32 + kt) * 24) + es * 4 + nf2) * 64 +
                    (size_t)(qd * 16 + l2)) * 8;
      *(bf16x8*)(dst + off) = val;
    }
  } else {
    // pi on the key axis: key group (=quad) 1<->2 swap so attn's permlane
    // exchange lands P positions on matching V rows.
    int q2 = quad ^ (((quad ^ (quad >> 1)) & 1) * 3);  // 0,2,1,3
#pragma unroll
    for (int i = 0; i < 4; i++) {
      int kt = (mtb * 2 + wm) & 31;
      int ks2 = (i >> 1) & 1;
      int qd2 = (i * 2 + (q2 >> 1)) & 3;
#pragma unroll
      for (int j = 0; j < 2; j++) {
        int ef = c * 4 + wn * 2 + j;   // d = wn*32+j*16+ln -> d>>4 = wn*2+j
        size_t off = ((size_t)((bhx * 32 + kt) * 24 + ks2 * 12 + ef)) * 512 +
                     (qd2 * 16 + ln) * 8 + (q2 & 1) * 4;
        bf16x4 val = { f2bf(acc[i][j][0]), f2bf(acc[i][j][1]),
                       f2bf(acc[i][j][2]), f2bf(acc[i][j][3]) };
        *(bf16x4*)(vp + off) = val;
      }
    }
  }
}

// ---------------------------------------------------------------- attn (R1, proven 54.0us)
// Split-K(2), 32-key dbuf tiles, one barrier/iter, S^T operand swap,
// in-register P exchange (cvt_pk + 2x permlane32_swap, pi matched by
// qkv_gemm's V layout), deferred PV: iter kt runs QK(kt)+PV(kt-1) as one
// 48-MFMA setprio cluster; softmax VALU overlaps the MFMA drain. V staged
// one iter later than K so plain double-buffering stays race-free.
__global__ __launch_bounds__(256, 2) void attn(const short* __restrict__ qp,
                                               const short* __restrict__ kp,
                                               const short* __restrict__ vp,
                                               short* __restrict__ opart,
                                               float* __restrict__ lpart) {
  __shared__ __align__(16) short pool[25600];  // K dbuf 2x6144 | V dbuf 2x6144 | tp [128][200]
  int pair = blockIdx.x, qt = blockIdx.y;
  int bh = pair & 15, kh = pair >> 4;
  int tid = threadIdx.x, wave = tid >> 6, lane = tid & 63;
  int ln = lane & 15, quad = lane >> 4;

  bf16x8 qf[2][6];
#pragma unroll
  for (int rg = 0; rg < 2; rg++) {
    int fi = wave * 2 + rg;
    const short* qb = qp +
        ((size_t)(bh * 32 + qt * 2 + (fi >> 2)) * 24 + (fi & 3)) * 512 + lane * 8;
#pragma unroll
    for (int es = 0; es < 6; es++) qf[rg][es] = *(const bf16x8*)(qb + es * 2048);
  }

  float l_r[2] = {0.f, 0.f};
  f32x4 acc[2][12] = {};
  bf16x8 pa[2] = {};  // P fragments of the previous key tile (registers)
  const short* gKb = kp + (size_t)(bh * 32 + kh * 16) * 12288;
  const short* gVb = vp + (size_t)(bh * 32 + kh * 16) * 12288;

  auto stage_k = [&](int k32) {
    const short* g64 = gKb + (size_t)(k32 >> 1) * 12288;
    int half = k32 & 1;
    short* Kd = pool + (k32 & 1) * 6144;
#pragma unroll
    for (int i = 0; i < 3; i++) {
      int q = i * 256 + tid;
      int f = q >> 6, l = q & 63;
      int es = f >> 1, nfl = f & 1;
      load_lds16(g64 + (size_t)(es * 4 + half * 2 + nfl) * 512 + l * 8, Kd + q * 8);
    }
  };
  auto stage_v = [&](int k32) {
    const short* g64 = gVb + (size_t)(k32 >> 1) * 12288;
    int half = k32 & 1;
    short* Vd = pool + 12288 + (k32 & 1) * 6144;
#pragma unroll
    for (int i = 0; i < 3; i++) {
      int q = i * 256 + tid;
      int f = q >> 6, l = q & 63;
      load_lds16(g64 + (size_t)(half * 12 + f) * 512 + l * 8, Vd + q * 8);
    }
  };

  stage_k(0);
  for (int kt = 0; kt < 32; kt++) {
    int b = kt & 1;
    __syncthreads();  // K(kt), V(kt-1) deposited; K(kt-1)/V(kt-2) reads done
    if (kt < 31) stage_k(kt + 1);  // -> K[b^1], dead buffer
    stage_v(kt);                   // -> V[b], dead buffer (V(kt-2))
    const short* Kl = pool + b * 6144;
    const short* Vl = pool + 12288 + ((kt - 1) & 1) * 6144;  // unused at kt=0

    __builtin_amdgcn_s_setprio(1);
    // S^T = K Q^T: row=key(quad*4+jj), col=qrow(ln)
    f32x4 s[2][2] = {};
#pragma unroll
    for (int es = 0; es < 6; es++) {
#pragma unroll
      for (int nfl = 0; nfl < 2; nfl++) {
        bf16x8 kf = *(const bf16x8*)&Kl[(es * 2 + nfl) * 512 + lane * 8];
        s[0][nfl] = __builtin_amdgcn_mfma_f32_16x16x32_bf16(kf, qf[0][es], s[0][nfl], 0, 0, 0);
        s[1][nfl] = __builtin_amdgcn_mfma_f32_16x16x32_bf16(kf, qf[1][es], s[1][nfl], 0, 0, 0);
      }
    }
    if (kt > 0) {
#pragma unroll
      for (int ef = 0; ef < 12; ef++) {
        bf16x8 v0 = *(const bf16x8*)&Vl[ef * 512 + lane * 8];
        acc[0][ef] = __builtin_amdgcn_mfma_f32_16x16x32_bf16(pa[0], v0, acc[0][ef], 0, 0, 0);
        acc[1][ef] = __builtin_amdgcn_mfma_f32_16x16x32_bf16(pa[1], v0, acc[1][ef], 0, 0, 0);
      }
    }
    __builtin_amdgcn_s_setprio(0);

    // softmax for tile kt: exp2 -> bf16 pack -> cross-half swap.
    // Source lane (quad,ln) holds keys {nfl*16+quad*4+jj} of q-row ln.
    // After 2x permlane32_swap, dest lane (quad,ln) holds PV positions
    // quad*8..+7 = keys under pi (quad-groups 1<->2 swapped) — matching V.
#pragma unroll
    for (int rg = 0; rg < 2; rg++) {
      float p0[4], p1[4];
#pragma unroll
      for (int jj = 0; jj < 4; jj++) {
        float e0 = __builtin_amdgcn_exp2f(s[rg][0][jj]);
        float e1 = __builtin_amdgcn_exp2f(s[rg][1][jj]);
        p0[jj] = e0; p1[jj] = e1;
        l_r[rg] += e0;
        l_r[rg] += e1;
      }
      unsigned a0, a1, b0, b1;
      asm("v_cvt_pk_bf16_f32 %0, %1, %2" : "=v"(a0) : "v"(p0[0]), "v"(p0[1]));
      asm("v_cvt_pk_bf16_f32 %0, %1, %2" : "=v"(a1) : "v"(p0[2]), "v"(p0[3]));
      asm("v_cvt_pk_bf16_f32 %0, %1, %2" : "=v"(b0) : "v"(p1[0]), "v"(p1[1]));
      asm("v_cvt_pk_bf16_f32 %0, %1, %2" : "=v"(b1) : "v"(p1[2]), "v"(p1[3]));
      auto r0 = __builtin_amdgcn_permlane32_swap(a0, b0, false, false);
      auto r1 = __builtin_amdgcn_permlane32_swap(a1, b1, false, false);
      union { unsigned u[4]; bf16x8 v; } pk;
      pk.u[0] = r0[0]; pk.u[1] = r1[0]; pk.u[2] = r0[1]; pk.u[3] = r1[1];
      pa[rg] = pk.v;
    }
  }

  // epilogue PV for the last tile: V(31) in buf 1
  __syncthreads();
  {
    const short* Vl = pool + 12288 + 6144;
#pragma unroll
    for (int ef = 0; ef < 12; ef++) {
      bf16x8 v0 = *(const bf16x8*)&Vl[ef * 512 + lane * 8];
      acc[0][ef] = __builtin_amdgcn_mfma_f32_16x16x32_bf16(pa[0], v0, acc[0][ef], 0, 0, 0);
      acc[1][ef] = __builtin_amdgcn_mfma_f32_16x16x32_bf16(pa[1], v0, acc[1][ef], 0, 0, 0);
    }
  }

  // l reduce: keys were distributed across quads (and nfl, already summed)
#pragma unroll
  for (int rg = 0; rg < 2; rg++) {
    l_r[rg] += __shfl_xor(l_r[rg], 16, 64);
    l_r[rg] += __shfl_xor(l_r[rg], 32, 64);
  }

  __syncthreads();  // all V reads done; pool reused as tp [128][200]
  short* tp = pool;
#pragma unroll
  for (int rg = 0; rg < 2; rg++)
#pragma unroll
    for (int jj = 0; jj < 4; jj++) {
      int row = (wave * 2 + rg) * 16 + quad * 4 + jj;
#pragma unroll
      for (int ef = 0; ef < 12; ef++)
        tp[row * 200 + ef * 16 + ln] = f2bf(acc[rg][ef][jj]);
    }
  __syncthreads();
  const size_t obase = ((size_t)(kh * 16 + bh) * 2048 + qt * 128) * 192;
#pragma unroll
  for (int rep = 0; rep < 12; rep++) {
    int gi = rep * 256 + tid;
    int row = gi / 24, c8 = gi - row * 24;
    *(bf16x8*)(opart + obase + (size_t)row * 192 + c8 * 8) =
        *(const bf16x8*)&tp[row * 200 + c8 * 8];
  }
  int lb = (kh * 16 + bh) * 2048 + qt * 128;
  if (quad == 0) {
#pragma unroll
    for (int rg = 0; rg < 2; rg++)
      lpart[lb + (wave * 2 + rg) * 16 + ln] = l_r[rg];
  }
}

// ---------------------------------------------------------------- out_gemm v6
// c-FUSED merge + projection. NEW: 512 threads / 8 waves per block (was 256/4
// = 1 wave/SIMD, zero TLP for a latency-heavy merge + ds_read->MFMA chain).
// Same grid 256, same per-block work and memory footprint — each wave now
// covers 2 n-tiles (jf<2), merge/store reps halve. 2 waves/SIMD TLP.
__global__ __launch_bounds__(512) void out_gemm(const short* __restrict__ opart,
                                                const float* __restrict__ lpart,
                                                const short* __restrict__ wop,
                                                float* __restrict__ out) {
  __shared__ __align__(16) float pool_f[12352];  // 49408 B
  short* Al = (short*)pool_f;                    // [3][16 ks][512]
  int mtb = blockIdx.x;
  int tid = threadIdx.x, wave = tid >> 6, lane = tid & 63;
  int ln = lane & 15, quad = lane >> 4;
  const size_t HSTR = (size_t)16 * 2048 * 192;

#pragma unroll
  for (int rep = 0; rep < 6; rep++) {
    int g = rep * 512 + tid;
    int c = g >> 10, inner = g & 1023;
    int d8 = inner & 7, h = (inner >> 3) & 7, row16 = inner >> 6;
    int t = mtb * 16 + row16, b = t >> 11, n = t & 2047;
    int bh = b * 8 + h;
    size_t src = ((size_t)bh * 2048 + n) * 192 + c * 64 + d8 * 8;
    bf16x8 o1 = *(const bf16x8*)(opart + src);
    bf16x8 o2 = *(const bf16x8*)(opart + HSTR + src);
    float l = lpart[bh * 2048 + n] + lpart[32768 + bh * 2048 + n];
    float inv = 1.f / l;
    bf16x8 r;
#pragma unroll
    for (int j = 0; j < 8; j++) r[j] = f2bf((bf2f(o1[j]) + bf2f(o2[j])) * inv);
    int ks = h * 2 + (d8 >> 2), qd = d8 & 3;
    *(bf16x8*)&Al[c * 8192 + ks * 512 + (qd * 16 + row16) * 8] = r;
  }
  __syncthreads();

  f32x4 acc[3][2] = {};
  for (int ks = 0; ks < 16; ks++) {
    bf16x8 af[3];
#pragma unroll
    for (int c = 0; c < 3; c++) af[c] = *(const bf16x8*)&Al[c * 8192 + ks * 512 + lane * 8];
#pragma unroll
    for (int jf = 0; jf < 2; jf++) {
      int nt = wave * 2 + jf;
      bf16x8 bfr = *(const bf16x8*)(wop + (size_t)(nt * 16 + ks) * 512 + lane * 8);
#pragma unroll
      for (int c = 0; c < 3; c++)
        acc[c][jf] = __builtin_amdgcn_mfma_f32_16x16x32_bf16(af[c], bfr, acc[c][jf], 0, 0, 0);
    }
  }
  __syncthreads();  // Al dead; reuse pool_f for the fp32 out-tile [16][772]
#pragma unroll
  for (int c = 0; c < 3; c++)
#pragma unroll
    for (int jf = 0; jf < 2; jf++) {
      int o2 = (wave * 2 + jf) * 16 + ln;
#pragma unroll
      for (int jj = 0; jj < 4; jj++)
        pool_f[(quad * 4 + jj) * 772 + o2 * 3 + c] = acc[c][jf][jj];
    }
  __syncthreads();
  float* ob = out + (size_t)mtb * 12288;
#pragma unroll
  for (int rep = 0; rep < 6; rep++) {
    int idx = rep * 512 + tid;
    int row = idx / 192, col4 = idx - row * 192;
    *(float4v*)(ob + row * 768 + col4 * 4) =
        *(const float4v*)(pool_f + row * 772 + col4 * 4);
  }
}

// ---------------------------------------------------------------- launch
extern "C" void kernel_launch(void* const* d_in, const int* in_sizes, int n_in,
                              void* d_out, int out_size, void* d_ws, size_t ws_size,
                              hipStream_t stream) {
  const float* x  = (const float*)d_in[0];
  const float* Wq = (const float*)d_in[1];
  const float* Wk = (const float*)d_in[2];
  const float* Wv = (const float*)d_in[3];
  const float* Wo = (const float*)d_in[4];
  float* out = (float*)d_out;

  short* ws    = (short*)d_ws;
  short* xcp   = ws;                                   // 3*4096*256
  short* wqkvp = xcp + 3 * NTOK * CIN;                 // 1536*256
  short* wop   = wqkvp + 1536 * 256;                   // 256*512
  short* qp    = wop + 256 * 512;                      // 16*2048*192
  short* kp    = qp + (size_t)BHTOT * NSEQ * E;
  short* vp    = kp + (size_t)BHTOT * NSEQ * E;
  short* opart = vp + (size_t)BHTOT * NSEQ * E;        // 2*16*2048*192
  float* lpart = (float*)xcp;   // ALIAS: xcp dead after qkv_gemm (stream order)

  prep<<<2304, 256, 0, stream>>>(x, Wq, Wk, Wv, Wo, xcp, wqkvp, wop);
  qkv_gemm<<<dim3(24, 32, 3), 256, 0, stream>>>(xcp, wqkvp, qp, kp, vp);
  attn<<<dim3(32, 16), 256, 0, stream>>>(qp, kp, vp, opart, lpart);
  out_gemm<<<256, 512, 0, stream>>>(opart, lpart, wop, out);
}